// Round 6
// baseline (1755.784 us; speedup 1.0000x reference)
//
#include <hip/hip_runtime.h>
#include <cmath>

typedef unsigned short ushort_t;
typedef __attribute__((ext_vector_type(8))) short short8;
typedef __attribute__((ext_vector_type(4))) float f32x4;
typedef __attribute__((ext_vector_type(4))) short short4v;

static constexpr int NSEQ = 2048, DM = 1024, DH = 64, DI = 512;
static constexpr size_t NN = (size_t)NSEQ * NSEQ;

__device__ __forceinline__ ushort_t f2b(float v) {
    unsigned u = __float_as_uint(v);
    return (ushort_t)((u + 0x7fffu + ((u >> 16) & 1u)) >> 16);  // RTNE
}
__device__ __forceinline__ float b2f(ushort_t b) { return __uint_as_float(((unsigned)b) << 16); }
__device__ __forceinline__ float sigm(float x) { return 1.f / (1.f + expf(-x)); }
__device__ __forceinline__ float silu(float x) { return x / (1.f + expf(-x)); }

#define MFMA16(a, b, c) __builtin_amdgcn_mfma_f32_16x16x32_bf16(a, b, c, 0, 0, 0)

__device__ __forceinline__ int swz_off(int row, int c) {
    return row * 32 + ((c ^ ((row >> 1) & 3)) << 3);
}
__device__ __forceinline__ short8 sfrag(const ushort_t* t, int row0, int lane) {
    const int row = row0 + (lane & 15);
    return *(const short8*)(t + swz_off(row, lane >> 4));
}
__device__ __forceinline__ short8 keep_low(short8 v, int n) {  // zero elements e >= n
#pragma unroll
    for (int e = 0; e < 8; ++e) v[e] = (e < n) ? v[e] : (short)0;
    return v;
}
__device__ __forceinline__ short8 zero_low(short8 v, int n) {  // zero elements e < n
#pragma unroll
    for (int e = 0; e < 8; ++e) v[e] = (e < n) ? (short)0 : v[e];
    return v;
}

// ---- hi/lo staging (A,B both 128x32) --------------------------------------------
struct SHL { short8 v[8]; };
__device__ __forceinline__ void ldhl(const ushort_t* ah, const ushort_t* al,
                                     const ushort_t* bh, const ushort_t* bl,
                                     int lda, int ldb, SHL& s) {
    const int tid = threadIdx.x, row = tid >> 1, c0 = (tid & 1) * 2;
    const size_t oa = (size_t)row * lda + c0 * 8;
    const size_t ob = (size_t)row * ldb + c0 * 8;
    s.v[0] = *(const short8*)(ah + oa); s.v[1] = *(const short8*)(ah + oa + 8);
    s.v[2] = *(const short8*)(al + oa); s.v[3] = *(const short8*)(al + oa + 8);
    s.v[4] = *(const short8*)(bh + ob); s.v[5] = *(const short8*)(bh + ob + 8);
    s.v[6] = *(const short8*)(bl + ob); s.v[7] = *(const short8*)(bl + ob + 8);
}
__device__ __forceinline__ void sthl(ushort_t* buf, const SHL& s) {
    const int tid = threadIdx.x, row = tid >> 1, c0 = (tid & 1) * 2;
    const int o0 = swz_off(row, c0), o1 = swz_off(row, c0 + 1);
    *(short8*)(buf + o0) = s.v[0];         *(short8*)(buf + o1) = s.v[1];
    *(short8*)(buf + 4096 + o0) = s.v[2];  *(short8*)(buf + 4096 + o1) = s.v[3];
    *(short8*)(buf + 8192 + o0) = s.v[4];  *(short8*)(buf + 8192 + o1) = s.v[5];
    *(short8*)(buf + 12288 + o0) = s.v[6]; *(short8*)(buf + 12288 + o1) = s.v[7];
}
__device__ __forceinline__ void mm_hl(const ushort_t* buf, int mb, int nb, int lane,
                                      f32x4 (&acc)[4][4]) {
    short8 fah[4], fal[4], fbh[4], fbl[4];
#pragma unroll
    for (int i = 0; i < 4; ++i) {
        fah[i] = sfrag(buf, mb + i * 16, lane);
        fal[i] = sfrag(buf + 4096, mb + i * 16, lane);
    }
#pragma unroll
    for (int j = 0; j < 4; ++j) {
        fbh[j] = sfrag(buf + 8192, nb + j * 16, lane);
        fbl[j] = sfrag(buf + 12288, nb + j * 16, lane);
    }
#pragma unroll
    for (int i = 0; i < 4; ++i)
#pragma unroll
        for (int j = 0; j < 4; ++j) {
            acc[i][j] = MFMA16(fah[i], fbh[j], acc[i][j]);
            acc[i][j] = MFMA16(fah[i], fbl[j], acc[i][j]);
            acc[i][j] = MFMA16(fal[i], fbh[j], acc[i][j]);
        }
}

// ---- one-shot f32 -> bf16 hi(/lo) -----------------------------------------------
__global__ __launch_bounds__(256) void k_cvt(const float4* __restrict__ src,
                                             ushort_t* __restrict__ hi,
                                             ushort_t* __restrict__ lo, int n4, int has_lo) {
    for (int i = blockIdx.x * 256 + threadIdx.x; i < n4; i += gridDim.x * 256) {
        float4 f = src[i];
        float a[4] = {f.x, f.y, f.z, f.w};
        short4v hv, lv;
#pragma unroll
        for (int j = 0; j < 4; ++j) {
            ushort_t h = f2b(a[j]);
            hv[j] = (short)h;
            lv[j] = (short)f2b(a[j] - b2f(h));
        }
        *(short4v*)(hi + (size_t)i * 4) = hv;
        if (has_lo) *(short4v*)(lo + (size_t)i * 4) = lv;
    }
}

// ---- proj: qkv = x @ Wqkv^T, 2-deep pipelined, scatter + vcT --------------------
__global__ __launch_bounds__(256) void k_proj(const ushort_t* __restrict__ xh,
                                              const ushort_t* __restrict__ xl,
                                              const ushort_t* __restrict__ wh,
                                              const ushort_t* __restrict__ wl,
                                              ushort_t* __restrict__ qh, ushort_t* __restrict__ ql,
                                              ushort_t* __restrict__ vcT) {
    __shared__ __align__(16) ushort_t lds[2][16384];
    const int m0 = blockIdx.y * 128, n0 = blockIdx.x * 128;
    const int l = threadIdx.x & 63, w = threadIdx.x >> 6;
    const int mb = (w >> 1) * 64, nb = (w & 1) * 64;
    const ushort_t* pah = xh + (size_t)m0 * DM;
    const ushort_t* pal = xl + (size_t)m0 * DM;
    const ushort_t* pbh = wh + (size_t)n0 * DM;
    const ushort_t* pbl = wl + (size_t)n0 * DM;
    SHL s0, s1;
    ldhl(pah, pal, pbh, pbl, DM, DM, s0);
    ldhl(pah + 32, pal + 32, pbh + 32, pbl + 32, DM, DM, s1);
    f32x4 acc[4][4] = {};
    for (int t = 0; t < 32; t += 2) {
        sthl(lds[0], s0);
        __syncthreads();
        if (t + 2 < 32) { int k0 = (t + 2) * 32; ldhl(pah + k0, pal + k0, pbh + k0, pbl + k0, DM, DM, s0); }
        mm_hl(lds[0], mb, nb, l, acc);
        sthl(lds[1], s1);
        __syncthreads();
        if (t + 3 < 32) { int k0 = (t + 3) * 32; ldhl(pah + k0, pal + k0, pbh + k0, pbl + k0, DM, DM, s1); }
        mm_hl(lds[1], mb, nb, l, acc);
    }
#pragma unroll
    for (int i = 0; i < 4; ++i)
#pragma unroll
        for (int j = 0; j < 4; ++j)
#pragma unroll
            for (int r = 0; r < 4; ++r) {
                int m = m0 + mb + i * 16 + (l >> 4) * 4 + r;
                int n = n0 + nb + j * 16 + (l & 15);
                float v = acc[i][j][r];
                int tt = n >> 9, head = (n >> 6) & 7, dd = n & 63;
                int b = m >> 11, np = m & 2047;
                if (tt == 0 || tt == 3) v *= 0.125f;
                ushort_t h = f2b(v), lo = f2b(v - b2f(h));
                size_t off = (size_t)(tt * 16 + b * 8 + head) * 131072 + (size_t)np * 64 + dd;
                qh[off] = h;
                ql[off] = lo;
                if (tt == 5) vcT[(size_t)(b * 8 + head) * 131072 + (size_t)dd * 2048 + np] = h;
            }
}

// ---- tl: mode0 t1->P lower, mode1 look->P upper, mode2 Sc->sc fp32 --------------
__global__ __launch_bounds__(256) void k_tl(const ushort_t* __restrict__ qkvh,
                                            const ushort_t* __restrict__ qkvl,
                                            ushort_t* __restrict__ Ph, ushort_t* __restrict__ Pl,
                                            float* __restrict__ scb, int g0, int g) {
    const int bx = blockIdx.x, by = blockIdx.y;
    const int mode = blockIdx.z / g, z = blockIdx.z % g, hh = g0 + z;
    if (mode == 1 ? (bx < by) : (bx > by)) return;
    const int ta = (mode == 1) ? 0 : 3;
    const int tb = (mode == 0) ? 2 : ((mode == 1) ? 1 : 4);
    const ushort_t* ah = qkvh + ((size_t)(ta * 16 + hh)) * 131072 + (size_t)(by * 128) * 64;
    const ushort_t* al = qkvl + ((size_t)(ta * 16 + hh)) * 131072 + (size_t)(by * 128) * 64;
    const ushort_t* bh = qkvh + ((size_t)(tb * 16 + hh)) * 131072 + (size_t)(bx * 128) * 64;
    const ushort_t* bl = qkvl + ((size_t)(tb * 16 + hh)) * 131072 + (size_t)(bx * 128) * 64;
    __shared__ __align__(16) ushort_t lds[2][16384];
    const int l = threadIdx.x & 63, w = threadIdx.x >> 6;
    const int mb = (w >> 1) * 64, nb = (w & 1) * 64;
    SHL s0, s1;
    ldhl(ah, al, bh, bl, 64, 64, s0);
    ldhl(ah + 32, al + 32, bh + 32, bl + 32, 64, 64, s1);
    f32x4 acc[4][4] = {};
    sthl(lds[0], s0);
    __syncthreads();
    mm_hl(lds[0], mb, nb, l, acc);
    sthl(lds[1], s1);
    __syncthreads();
    mm_hl(lds[1], mb, nb, l, acc);
    if (mode == 0) {
        ushort_t* ph = Ph + (size_t)z * NN;
        ushort_t* pl = Pl + (size_t)z * NN;
#pragma unroll
        for (int i = 0; i < 4; ++i)
#pragma unroll
            for (int j = 0; j < 4; ++j)
#pragma unroll
                for (int r = 0; r < 4; ++r) {
                    int gi = by * 128 + mb + i * 16 + (l >> 4) * 4 + r;
                    int gj = bx * 128 + nb + j * 16 + (l & 15);
                    if (gj <= gi) {
                        float v = acc[i][j][r];
                        ushort_t h = f2b(v);
                        ph[(size_t)gi * 2048 + gj] = h;
                        pl[(size_t)gi * 2048 + gj] = f2b(v - b2f(h));
                    }
                }
    } else if (mode == 1) {
        ushort_t* ph = Ph + (size_t)z * NN;
        ushort_t* pl = Pl + (size_t)z * NN;
#pragma unroll
        for (int i = 0; i < 4; ++i)
#pragma unroll
            for (int j = 0; j < 4; ++j)
#pragma unroll
                for (int r = 0; r < 4; ++r) {
                    int gk = by * 128 + mb + i * 16 + (l >> 4) * 4 + r;
                    int gj = bx * 128 + nb + j * 16 + (l & 15);
                    if (gj > gk) {
                        float v = sigm(acc[i][j][r]);
                        ushort_t h = f2b(v);
                        ph[(size_t)gk * 2048 + gj] = h;
                        pl[(size_t)gk * 2048 + gj] = f2b(v - b2f(h));
                    }
                }
    } else {
        float* so = scb + (size_t)z * NN;
#pragma unroll
        for (int i = 0; i < 4; ++i)
#pragma unroll
            for (int j = 0; j < 4; ++j)
#pragma unroll
                for (int r = 0; r < 4; ++r) {
                    int gi = by * 128 + mb + i * 16 + (l >> 4) * 4 + r;
                    int gk = bx * 128 + nb + j * 16 + (l & 15);
                    if (gk <= gi) so[(size_t)gi * 2048 + gk] = acc[i][j][r];
                }
    }
}

// ---- su: partial Su over half j-range; phase1 accumulates -----------------------
__global__ __launch_bounds__(256) void k_su(const ushort_t* __restrict__ Ph,
                                            const ushort_t* __restrict__ Pl,
                                            float* __restrict__ sub, int phase) {
    const int bxk = blockIdx.x, byi = blockIdx.y;
    if (bxk > byi) return;
    const int z = blockIdx.z;
    const ushort_t* ph = Ph + (size_t)z * NN;
    const ushort_t* pl = Pl + (size_t)z * NN;
    const int nsu = (byi - bxk + 1) * 4, h1 = nsu >> 1;
    const int t0 = phase ? h1 : 0, nt = phase ? (nsu - h1) : h1;
    const int jbase = bxk * 128 + t0 * 32;
    __shared__ __align__(16) ushort_t lds[2][16384];
    const int l = threadIdx.x & 63, w = threadIdx.x >> 6;
    const int mb = (w >> 1) * 64, nb = (w & 1) * 64;
    const int tid = threadIdx.x, row = tid >> 1, c0 = (tid & 1) * 2;
    const int ia = byi * 128 + row, kb = bxk * 128 + row;
    const ushort_t* arh = ph + (size_t)ia * 2048;
    const ushort_t* arl = pl + (size_t)ia * 2048;
    const ushort_t* brh = ph + (size_t)kb * 2048;
    const ushort_t* brl = pl + (size_t)kb * 2048;

    auto LDM = [&](SHL& s, int step) {
        const int j0 = jbase + step * 32;
        const int ja = j0 + c0 * 8, jb2 = ja + 8;
        s.v[0] = *(const short8*)(arh + ja); s.v[1] = *(const short8*)(arh + jb2);
        s.v[2] = *(const short8*)(arl + ja); s.v[3] = *(const short8*)(arl + jb2);
        s.v[4] = *(const short8*)(brh + ja); s.v[5] = *(const short8*)(brh + jb2);
        s.v[6] = *(const short8*)(brl + ja); s.v[7] = *(const short8*)(brl + jb2);
        const int ka0 = ia - ja + 1, ka1 = ia - jb2 + 1;   // A keep j<=i
        const int zb0 = kb - ja + 1, zb1 = kb - jb2 + 1;   // B zero j<=k
        s.v[0] = keep_low(s.v[0], ka0); s.v[1] = keep_low(s.v[1], ka1);
        s.v[2] = keep_low(s.v[2], ka0); s.v[3] = keep_low(s.v[3], ka1);
        s.v[4] = zero_low(s.v[4], zb0); s.v[5] = zero_low(s.v[5], zb1);
        s.v[6] = zero_low(s.v[6], zb0); s.v[7] = zero_low(s.v[7], zb1);
    };
    SHL s0, s1;
    LDM(s0, 0);
    LDM(s1, 1);
    f32x4 acc[4][4] = {};
    for (int t = 0; t < nt; t += 2) {
        sthl(lds[0], s0);
        __syncthreads();
        if (t + 2 < nt) LDM(s0, t + 2);
        mm_hl(lds[0], mb, nb, l, acc);
        sthl(lds[1], s1);
        __syncthreads();
        if (t + 3 < nt) LDM(s1, t + 3);
        mm_hl(lds[1], mb, nb, l, acc);
    }
    float* so = sub + (size_t)z * NN;
#pragma unroll
    for (int i = 0; i < 4; ++i)
#pragma unroll
        for (int j = 0; j < 4; ++j)
#pragma unroll
            for (int r = 0; r < 4; ++r) {
                int gi = byi * 128 + mb + i * 16 + (l >> 4) * 4 + r;
                int gk = bxk * 128 + nb + j * 16 + (l & 15);
                size_t o = (size_t)gi * 2048 + gk;
                if (phase) so[o] += acc[i][j][r];
                else so[o] = acc[i][j][r];
            }
}

// ---- softmax: score = sc - silu(su), row softmax (k<=i) -> bf16 attn ------------
__global__ __launch_bounds__(256) void k_softmax(const float* __restrict__ scb,
                                                 const float* __restrict__ sub,
                                                 ushort_t* __restrict__ attn) {
    const int z = blockIdx.x >> 11, i = blockIdx.x & 2047;
    const float* scr = scb + (size_t)z * NN + (size_t)i * 2048;
    const float* sur = sub + (size_t)z * NN + (size_t)i * 2048;
    ushort_t* arow = attn + (size_t)z * NN + (size_t)i * 2048;
    const int tid = threadIdx.x, k0 = tid * 8;
    float4 a0 = *(const float4*)(scr + k0), a1 = *(const float4*)(scr + k0 + 4);
    float4 b0 = *(const float4*)(sur + k0), b1 = *(const float4*)(sur + k0 + 4);
    float sv[8] = {a0.x, a0.y, a0.z, a0.w, a1.x, a1.y, a1.z, a1.w};
    float uv[8] = {b0.x, b0.y, b0.z, b0.w, b1.x, b1.y, b1.z, b1.w};
    float s[8];
    float m = -3e38f;
#pragma unroll
    for (int e = 0; e < 8; ++e) {
        s[e] = (k0 + e <= i) ? (sv[e] - silu(uv[e])) : -3e38f;
        m = fmaxf(m, s[e]);
    }
    __shared__ float red[256];
    red[tid] = m;
    __syncthreads();
    for (int ss = 128; ss; ss >>= 1) {
        if (tid < ss) red[tid] = fmaxf(red[tid], red[tid + ss]);
        __syncthreads();
    }
    m = red[0];
    __syncthreads();
    float p[8], sum = 0.f;
#pragma unroll
    for (int e = 0; e < 8; ++e) { p[e] = expf(s[e] - m); sum += p[e]; }
    red[tid] = sum;
    __syncthreads();
    for (int ss = 128; ss; ss >>= 1) {
        if (tid < ss) red[tid] += red[tid + ss];
        __syncthreads();
    }
    const float inv = 1.f / red[0];
    const int lim = ((i >> 7) + 1) << 7;
    if (k0 < lim) {
        short8 o;
#pragma unroll
        for (int e = 0; e < 8; ++e) o[e] = (short)f2b(p[e] * inv);
        *(short8*)(arow + k0) = o;
    }
}

// ---- pv: split-k partial O chunks (fp32 into su area) ---------------------------
struct SPV { short8 a0, a1, b0; };
__global__ __launch_bounds__(256) void k_pv(const ushort_t* __restrict__ attn,
                                            const ushort_t* __restrict__ vcT,
                                            float* __restrict__ opbase, int g0) {
    const int byi = blockIdx.x, c = blockIdx.y, z = blockIdx.z;
    if (c * 4 > byi) return;
    const int hh = g0 + z;
    const int nkb = min(4, byi + 1 - c * 4), nt = nkb * 4;
    const ushort_t* ap = attn + (size_t)z * NN + (size_t)(byi * 128) * 2048 + c * 512;
    const ushort_t* vp = vcT + (size_t)hh * 131072 + c * 512;
    float* op = opbase + (size_t)z * NN + (size_t)(c * 2048) * 64;
    __shared__ __align__(16) ushort_t lds[2][6144];
    const int l = threadIdx.x & 63, w = threadIdx.x >> 6, mb = w * 32;
    const int tid = threadIdx.x;
    const int ra = tid >> 1, ca = (tid & 1) * 2;
    const int rb = tid >> 2, cb = tid & 3;
    auto LD = [&](SPV& s, int t) {
        int k0 = t * 32;
        s.a0 = *(const short8*)(ap + (size_t)ra * 2048 + k0 + ca * 8);
        s.a1 = *(const short8*)(ap + (size_t)ra * 2048 + k0 + ca * 8 + 8);
        s.b0 = *(const short8*)(vp + (size_t)rb * 2048 + k0 + cb * 8);
    };
    auto ST = [&](ushort_t* buf, const SPV& s) {
        int o0 = swz_off(ra, ca), o1 = swz_off(ra, ca + 1);
        *(short8*)(buf + o0) = s.a0;
        *(short8*)(buf + o1) = s.a1;
        *(short8*)(buf + 4096 + swz_off(rb, cb)) = s.b0;
    };
    SPV s0, s1;
    LD(s0, 0);
    LD(s1, 1);
    f32x4 acc[2][4] = {};
    for (int t = 0; t < nt; t += 2) {
        ST(lds[0], s0);
        __syncthreads();
        if (t + 2 < nt) LD(s0, t + 2);
        {
            short8 fa[2], fb[4];
#pragma unroll
            for (int i = 0; i < 2; ++i) fa[i] = sfrag(lds[0], mb + i * 16, l);
#pragma unroll
            for (int j = 0; j < 4; ++j) fb[j] = sfrag(lds[0] + 4096, j * 16, l);
#pragma unroll
            for (int i = 0; i < 2; ++i)
#pragma unroll
                for (int j = 0; j < 4; ++j) acc[i][j] = MFMA16(fa[i], fb[j], acc[i][j]);
        }
        ST(lds[1], s1);
        __syncthreads();
        if (t + 3 < nt) LD(s1, t + 3);
        {
            short8 fa[2], fb[4];
#pragma unroll
            for (int i = 0; i < 2; ++i) fa[i] = sfrag(lds[1], mb + i * 16, l);
#pragma unroll
            for (int j = 0; j < 4; ++j) fb[j] = sfrag(lds[1] + 4096, j * 16, l);
#pragma unroll
            for (int i = 0; i < 2; ++i)
#pragma unroll
                for (int j = 0; j < 4; ++j) acc[i][j] = MFMA16(fa[i], fb[j], acc[i][j]);
        }
    }
#pragma unroll
    for (int i = 0; i < 2; ++i)
#pragma unroll
        for (int j = 0; j < 4; ++j)
#pragma unroll
            for (int r = 0; r < 4; ++r) {
                int gi = byi * 128 + mb + i * 16 + (l >> 4) * 4 + r;
                int d = j * 16 + (l & 15);
                op[(size_t)gi * 64 + d] = acc[i][j][r];
            }
}

// ---- pv combine: sum chunks -> bf16 attno ---------------------------------------
__global__ __launch_bounds__(256) void k_pvc(const float* __restrict__ opall,
                                             ushort_t* __restrict__ attno, int g0) {
    const int z = blockIdx.x >> 9, rem = blockIdx.x & 511;
    const int i = rem * 4 + (threadIdx.x >> 6), d = threadIdx.x & 63;
    const int hh = g0 + z, b = hh >> 3, h = hh & 7;
    const float* op = opall + (size_t)z * NN;
    const int nc = (i >> 9) + 1;
    float a = 0.f;
    for (int c = 0; c < nc; ++c) a += op[(size_t)(c * 2048 + i) * 64 + d];
    attno[(size_t)(b * 2048 + i) * 512 + h * 64 + d] = f2b(a);
}

// ---- final = attno @ Wout^T, 2-deep pipelined single ----------------------------
struct SO { short8 a0, a1, b0, b1; };
__global__ __launch_bounds__(256) void k_outproj(const ushort_t* __restrict__ attno,
                                                 const ushort_t* __restrict__ woh,
                                                 float* __restrict__ out) {
    __shared__ __align__(16) ushort_t lds[2][8192];
    const int m0 = blockIdx.y * 128, n0 = blockIdx.x * 128;
    const int l = threadIdx.x & 63, w = threadIdx.x >> 6;
    const int mb = (w >> 1) * 64, nb = (w & 1) * 64;
    const int tid = threadIdx.x, row = tid >> 1, c0 = (tid & 1) * 2;
    const ushort_t* pa = attno + (size_t)(m0 + row) * DI + c0 * 8;
    const ushort_t* pb = woh + (size_t)(n0 + row) * DI + c0 * 8;
    auto LD = [&](SO& s, int t) {
        int k0 = t * 32;
        s.a0 = *(const short8*)(pa + k0); s.a1 = *(const short8*)(pa + k0 + 8);
        s.b0 = *(const short8*)(pb + k0); s.b1 = *(const short8*)(pb + k0 + 8);
    };
    auto ST = [&](ushort_t* buf, const SO& s) {
        int o0 = swz_off(row, c0), o1 = swz_off(row, c0 + 1);
        *(short8*)(buf + o0) = s.a0;        *(short8*)(buf + o1) = s.a1;
        *(short8*)(buf + 4096 + o0) = s.b0; *(short8*)(buf + 4096 + o1) = s.b1;
    };
    SO s0, s1;
    LD(s0, 0);
    LD(s1, 1);
    f32x4 acc[4][4] = {};
    for (int t = 0; t < 16; t += 2) {
        ST(lds[0], s0);
        __syncthreads();
        if (t + 2 < 16) LD(s0, t + 2);
        {
            short8 fa[4], fb[4];
#pragma unroll
            for (int i = 0; i < 4; ++i) fa[i] = sfrag(lds[0], mb + i * 16, l);
#pragma unroll
            for (int j = 0; j < 4; ++j) fb[j] = sfrag(lds[0] + 4096, nb + j * 16, l);
#pragma unroll
            for (int i = 0; i < 4; ++i)
#pragma unroll
                for (int j = 0; j < 4; ++j) acc[i][j] = MFMA16(fa[i], fb[j], acc[i][j]);
        }
        ST(lds[1], s1);
        __syncthreads();
        if (t + 3 < 16) LD(s1, t + 3);
        {
            short8 fa[4], fb[4];
#pragma unroll
            for (int i = 0; i < 4; ++i) fa[i] = sfrag(lds[1], mb + i * 16, l);
#pragma unroll
            for (int j = 0; j < 4; ++j) fb[j] = sfrag(lds[1] + 4096, nb + j * 16, l);
#pragma unroll
            for (int i = 0; i < 4; ++i)
#pragma unroll
                for (int j = 0; j < 4; ++j) acc[i][j] = MFMA16(fa[i], fb[j], acc[i][j]);
        }
    }
#pragma unroll
    for (int i = 0; i < 4; ++i)
#pragma unroll
        for (int j = 0; j < 4; ++j)
#pragma unroll
            for (int r = 0; r < 4; ++r) {
                int m = m0 + mb + i * 16 + (l >> 4) * 4 + r;
                int n = n0 + nb + j * 16 + (l & 15);
                out[(size_t)m * DM + n] = acc[i][j][r];
            }
}

extern "C" void kernel_launch(void* const* d_in, const int* in_sizes, int n_in,
                              void* d_out, int out_size, void* d_ws, size_t ws_size,
                              hipStream_t stream) {
    const float* x = (const float*)d_in[0];
    const float* Wqkv = (const float*)d_in[1];
    const float* Wout = (const float*)d_in[2];
    float* out = (float*)d_out;

    const size_t fixedb = 58720256ull;   // qh + ql + vcT + attno
    const size_t perh = 50331648ull;     // P h/l (16MB) + sc (16MB) + su (16MB)
    int g = 0;
    for (int cand : {16, 8, 4, 2, 1})
        if (fixedb + perh * (size_t)cand <= ws_size) { g = cand; break; }
    if (!g) return;

    ushort_t* qh = (ushort_t*)d_ws;          // 12,582,912 el
    ushort_t* ql = qh + 12582912;            // 12,582,912 el
    ushort_t* vcT = ql + 12582912;           // 2,097,152 el
    ushort_t* attno = vcT + 2097152;         // 2,097,152 el
    ushort_t* pool = attno + 2097152;
    // cvt/proj phase aliases (dead after k_proj):
    ushort_t* xh = pool;                     // 4,194,304
    ushort_t* xl = xh + 4194304;
    ushort_t* wh = xl + 4194304;             // 3,145,728
    ushort_t* wl = wh + 3145728;
    // group phase:
    ushort_t* Ph = pool;                                  // g * NN
    ushort_t* Pl = Ph + (size_t)g * NN;                   // g * NN
    float* scf = (float*)(Pl + (size_t)g * NN);           // g * NN f32
    float* suf = scf + (size_t)g * NN;                    // g * NN f32 (also opart)
    // outproj phase:
    ushort_t* woh = pool;

    k_cvt<<<dim3(1024), 256, 0, stream>>>((const float4*)x, xh, xl, 1048576, 1);
    k_cvt<<<dim3(1024), 256, 0, stream>>>((const float4*)Wqkv, wh, wl, 786432, 1);
    k_proj<<<dim3(24, 32), 256, 0, stream>>>(xh, xl, wh, wl, qh, ql, vcT);

    for (int g0 = 0; g0 < 16; g0 += g) {
        k_tl<<<dim3(16, 16, 3 * g), 256, 0, stream>>>(qh, ql, Ph, Pl, scf, g0, g);
        k_su<<<dim3(16, 16, g), 256, 0, stream>>>(Ph, Pl, suf, 0);
        k_su<<<dim3(16, 16, g), 256, 0, stream>>>(Ph, Pl, suf, 1);
        k_softmax<<<dim3(2048 * g), 256, 0, stream>>>(scf, suf, Ph);
        k_pv<<<dim3(16, 4, g), 256, 0, stream>>>(Ph, vcT, suf, g0);
        k_pvc<<<dim3(512 * g), 256, 0, stream>>>(suf, attno, g0);
    }

    k_cvt<<<dim3(512), 256, 0, stream>>>((const float4*)Wout, woh, nullptr, 131072, 0);
    k_outproj<<<dim3(8, 32), 256, 0, stream>>>(attno, woh, out);
}

// Round 7
// 1035.425 us; speedup vs baseline: 1.6957x; 1.6957x over previous
//
#include <hip/hip_runtime.h>
#include <cmath>

typedef unsigned short ushort_t;
typedef __attribute__((ext_vector_type(8))) short short8;
typedef __attribute__((ext_vector_type(4))) float f32x4;
typedef __attribute__((ext_vector_type(4))) short short4v;

static constexpr int NSEQ = 2048, DM = 1024, DI = 512;
static constexpr size_t NN = (size_t)NSEQ * NSEQ;

__device__ __forceinline__ ushort_t f2b(float v) {
    unsigned u = __float_as_uint(v);
    return (ushort_t)((u + 0x7fffu + ((u >> 16) & 1u)) >> 16);  // RTNE
}
__device__ __forceinline__ float b2f(ushort_t b) { return __uint_as_float(((unsigned)b) << 16); }
__device__ __forceinline__ float sigm(float x) { return 1.f / (1.f + expf(-x)); }
__device__ __forceinline__ float silu(float x) { return x / (1.f + expf(-x)); }

#define MFMA16(a, b, c) __builtin_amdgcn_mfma_f32_16x16x32_bf16(a, b, c, 0, 0, 0)

// ---- async global->LDS staging (m97 pattern): 16B/lane, linear LDS [rows][32] ---
__device__ __forceinline__ void gll16(const ushort_t* g, ushort_t* l) {
    __builtin_amdgcn_global_load_lds((const __attribute__((address_space(1))) void*)g,
                                     (__attribute__((address_space(3))) void*)l, 16, 0, 0);
}
// one wave stages rows [16*q0,16*q1) of a [.][32]-col slice (row stride ldg elems)
__device__ __forceinline__ void stage_rows(const ushort_t* g, int ldg, ushort_t* lds,
                                           int q0, int q1) {
    const int l = threadIdx.x & 63;
    const ushort_t* src = g + (size_t)(l >> 2) * ldg + (l & 3) * 8;
    for (int q = q0; q < q1; ++q)
        gll16(src + (size_t)(q * 16) * ldg, lds + q * 512);
}
// MFMA fragment from linear [row][32] LDS tile
__device__ __forceinline__ short8 lfrag(const ushort_t* t, int row0, int lane) {
    return *(const short8*)(t + (row0 + (lane & 15)) * 32 + ((lane >> 4) << 3));
}
// hi/lo 4x4 tile step: LDS = [Ah|Al|Bh|Bl] at 4096-entry strides
__device__ __forceinline__ void mm48(const ushort_t* lds, int mb, int nb, int lane,
                                     f32x4 (&acc)[4][4]) {
    short8 fah[4], fal[4], fbh[4], fbl[4];
#pragma unroll
    for (int i = 0; i < 4; ++i) {
        fah[i] = lfrag(lds, mb + i * 16, lane);
        fal[i] = lfrag(lds + 4096, mb + i * 16, lane);
    }
#pragma unroll
    for (int j = 0; j < 4; ++j) {
        fbh[j] = lfrag(lds + 8192, nb + j * 16, lane);
        fbl[j] = lfrag(lds + 12288, nb + j * 16, lane);
    }
#pragma unroll
    for (int i = 0; i < 4; ++i)
#pragma unroll
        for (int j = 0; j < 4; ++j) {
            acc[i][j] = MFMA16(fah[i], fbh[j], acc[i][j]);
            acc[i][j] = MFMA16(fah[i], fbl[j], acc[i][j]);
            acc[i][j] = MFMA16(fal[i], fbh[j], acc[i][j]);
        }
}

// ---- one-shot f32 -> bf16 hi(/lo) -----------------------------------------------
__global__ __launch_bounds__(256) void k_cvt(const float4* __restrict__ src,
                                             ushort_t* __restrict__ hi,
                                             ushort_t* __restrict__ lo, int n4, int has_lo) {
    for (int i = blockIdx.x * 256 + threadIdx.x; i < n4; i += gridDim.x * 256) {
        float4 f = src[i];
        float a[4] = {f.x, f.y, f.z, f.w};
        short4v hv, lv;
#pragma unroll
        for (int j = 0; j < 4; ++j) {
            ushort_t h = f2b(a[j]);
            hv[j] = (short)h;
            lv[j] = (short)f2b(a[j] - b2f(h));
        }
        *(short4v*)(hi + (size_t)i * 4) = hv;
        if (has_lo) *(short4v*)(lo + (size_t)i * 4) = lv;
    }
}

// ---- proj: qkv = x @ Wqkv^T (hi/lo), scatter + vcT ------------------------------
__global__ __launch_bounds__(256) void k_proj(const ushort_t* __restrict__ xh,
                                              const ushort_t* __restrict__ xl,
                                              const ushort_t* __restrict__ wh,
                                              const ushort_t* __restrict__ wl,
                                              ushort_t* __restrict__ qh, ushort_t* __restrict__ ql,
                                              ushort_t* __restrict__ vcT) {
    __shared__ __align__(16) ushort_t lds[16384];
    const int m0 = blockIdx.y * 128, n0 = blockIdx.x * 128;
    const int l = threadIdx.x & 63, w = threadIdx.x >> 6;
    const int mb = (w >> 1) * 64, nb = (w & 1) * 64;
    const ushort_t* mats[4] = {xh + (size_t)m0 * DM, xl + (size_t)m0 * DM,
                               wh + (size_t)n0 * DM, wl + (size_t)n0 * DM};
    f32x4 acc[4][4] = {};
    for (int t = 0; t < 32; ++t) {
        stage_rows(mats[w] + t * 32, DM, lds + w * 4096, 0, 8);
        __syncthreads();
        mm48(lds, mb, nb, l, acc);
        __syncthreads();
    }
#pragma unroll
    for (int i = 0; i < 4; ++i)
#pragma unroll
        for (int j = 0; j < 4; ++j)
#pragma unroll
            for (int r = 0; r < 4; ++r) {
                int m = m0 + mb + i * 16 + (l >> 4) * 4 + r;
                int n = n0 + nb + j * 16 + (l & 15);
                float v = acc[i][j][r];
                int tt = n >> 9, head = (n >> 6) & 7, dd = n & 63;
                int b = m >> 11, np = m & 2047;
                if (tt == 0 || tt == 3) v *= 0.125f;
                ushort_t h = f2b(v), lo = f2b(v - b2f(h));
                size_t off = (size_t)(tt * 16 + b * 8 + head) * 131072 + (size_t)np * 64 + dd;
                qh[off] = h;
                ql[off] = lo;
                if (tt == 5) vcT[(size_t)(b * 8 + head) * 131072 + (size_t)dd * 2048 + np] = h;
            }
}

// ---- tl: mode0 t1 = mask_lower(qc@vu^T), mode1 look = mask_up(sigm(qu@ku^T)) ----
__global__ __launch_bounds__(256) void k_tl(const ushort_t* __restrict__ qkvh,
                                            const ushort_t* __restrict__ qkvl,
                                            ushort_t* __restrict__ t1h, ushort_t* __restrict__ t1l,
                                            ushort_t* __restrict__ lkh, ushort_t* __restrict__ lkl,
                                            int g0) {
    const int bx = blockIdx.x, by = blockIdx.y;
    const int mode = blockIdx.z & 1, z = blockIdx.z >> 1, hh = g0 + z;
    if (mode == 0 ? (bx > by) : (bx < by)) return;
    const int ta = mode ? 0 : 3, tb = mode ? 1 : 2;
    __shared__ __align__(16) ushort_t lds[16384];
    const int l = threadIdx.x & 63, w = threadIdx.x >> 6;
    const int mb = (w >> 1) * 64, nb = (w & 1) * 64;
    const ushort_t* mats[4] = {
        qkvh + (size_t)(ta * 16 + hh) * 131072 + (size_t)(by * 128) * 64,
        qkvl + (size_t)(ta * 16 + hh) * 131072 + (size_t)(by * 128) * 64,
        qkvh + (size_t)(tb * 16 + hh) * 131072 + (size_t)(bx * 128) * 64,
        qkvl + (size_t)(tb * 16 + hh) * 131072 + (size_t)(bx * 128) * 64};
    f32x4 acc[4][4] = {};
    for (int t = 0; t < 2; ++t) {
        stage_rows(mats[w] + t * 32, 64, lds + w * 4096, 0, 8);
        __syncthreads();
        mm48(lds, mb, nb, l, acc);
        __syncthreads();
    }
    if (mode == 0) {
        ushort_t* th = t1h + (size_t)z * NN;
        ushort_t* tl = t1l + (size_t)z * NN;
#pragma unroll
        for (int i = 0; i < 4; ++i)
#pragma unroll
            for (int j = 0; j < 4; ++j)
#pragma unroll
                for (int r = 0; r < 4; ++r) {
                    int gi = by * 128 + mb + i * 16 + (l >> 4) * 4 + r;
                    int gj = bx * 128 + nb + j * 16 + (l & 15);
                    float v = (gj <= gi) ? acc[i][j][r] : 0.f;
                    ushort_t h = f2b(v);
                    th[(size_t)gi * 2048 + gj] = h;
                    tl[(size_t)gi * 2048 + gj] = f2b(v - b2f(h));
                }
    } else {
        ushort_t* lh = lkh + (size_t)z * NN;
        ushort_t* ll = lkl + (size_t)z * NN;
#pragma unroll
        for (int i = 0; i < 4; ++i)
#pragma unroll
            for (int j = 0; j < 4; ++j)
#pragma unroll
                for (int r = 0; r < 4; ++r) {
                    int gk = by * 128 + mb + i * 16 + (l >> 4) * 4 + r;
                    int gj = bx * 128 + nb + j * 16 + (l & 15);
                    float v = (gj > gk) ? sigm(acc[i][j][r]) : 0.f;
                    ushort_t h = f2b(v);
                    lh[(size_t)gk * 2048 + gj] = h;
                    ll[(size_t)gk * 2048 + gj] = f2b(v - b2f(h));
                }
    }
}

// ---- scores = qc_s@kc^T - silu(t1 @ look^T), fp32 out (k<=i) --------------------
__global__ __launch_bounds__(256) void k_scores(const ushort_t* __restrict__ t1h,
                                                const ushort_t* __restrict__ t1l,
                                                const ushort_t* __restrict__ lkh,
                                                const ushort_t* __restrict__ lkl,
                                                const ushort_t* __restrict__ qkvh,
                                                const ushort_t* __restrict__ qkvl,
                                                float* __restrict__ sc, int g0) {
    const int bxk = blockIdx.x, byi = blockIdx.y;
    if (bxk > byi) return;
    const int z = blockIdx.z, hh = g0 + z;
    __shared__ __align__(16) ushort_t lds[16384];
    const int l = threadIdx.x & 63, w = threadIdx.x >> 6;
    const int mb = (w >> 1) * 64, nb = (w & 1) * 64;
    const int nsu = (byi - bxk + 1) * 4, nt = nsu + 2;
    const ushort_t* jmats[4] = {
        t1h + (size_t)z * NN + (size_t)(byi * 128) * 2048 + bxk * 128,
        t1l + (size_t)z * NN + (size_t)(byi * 128) * 2048 + bxk * 128,
        lkh + (size_t)z * NN + (size_t)(bxk * 128) * 2048 + bxk * 128,
        lkl + (size_t)z * NN + (size_t)(bxk * 128) * 2048 + bxk * 128};
    const ushort_t* smats[4] = {
        qkvh + (size_t)(3 * 16 + hh) * 131072 + (size_t)(byi * 128) * 64,
        qkvl + (size_t)(3 * 16 + hh) * 131072 + (size_t)(byi * 128) * 64,
        qkvh + (size_t)(4 * 16 + hh) * 131072 + (size_t)(bxk * 128) * 64,
        qkvl + (size_t)(4 * 16 + hh) * 131072 + (size_t)(bxk * 128) * 64};
    f32x4 acc[4][4] = {};
    for (int t = 0; t < nt; ++t) {
        if (t < nsu) stage_rows(jmats[w] + t * 32, 2048, lds + w * 4096, 0, 8);
        else stage_rows(smats[w] + (t - nsu) * 32, 64, lds + w * 4096, 0, 8);
        __syncthreads();
        if (t == nsu) {
#pragma unroll
            for (int i = 0; i < 4; ++i)
#pragma unroll
                for (int j = 0; j < 4; ++j)
#pragma unroll
                    for (int r = 0; r < 4; ++r) acc[i][j][r] = -silu(acc[i][j][r]);
        }
        mm48(lds, mb, nb, l, acc);
        __syncthreads();
    }
    float* so = sc + (size_t)z * NN;
#pragma unroll
    for (int i = 0; i < 4; ++i)
#pragma unroll
        for (int j = 0; j < 4; ++j)
#pragma unroll
            for (int r = 0; r < 4; ++r) {
                int gi = byi * 128 + mb + i * 16 + (l >> 4) * 4 + r;
                int gk = bxk * 128 + nb + j * 16 + (l & 15);
                if (gk <= gi) so[(size_t)gi * 2048 + gk] = acc[i][j][r];
            }
}

// ---- row softmax (k<=i) -> bf16 attn (into t1h), zero-pad to 128-boundary -------
__global__ __launch_bounds__(256) void k_softmax(const float* __restrict__ scb,
                                                 ushort_t* __restrict__ attn) {
    const int z = blockIdx.x >> 11, i = blockIdx.x & 2047;
    const float* scr = scb + (size_t)z * NN + (size_t)i * 2048;
    ushort_t* arow = attn + (size_t)z * NN + (size_t)i * 2048;
    const int tid = threadIdx.x, k0 = tid * 8;
    float4 a0 = *(const float4*)(scr + k0), a1 = *(const float4*)(scr + k0 + 4);
    float sv[8] = {a0.x, a0.y, a0.z, a0.w, a1.x, a1.y, a1.z, a1.w};
    float s[8];
    float m = -3e38f;
#pragma unroll
    for (int e = 0; e < 8; ++e) {
        s[e] = (k0 + e <= i) ? sv[e] : -3e38f;
        m = fmaxf(m, s[e]);
    }
    __shared__ float red[256];
    red[tid] = m;
    __syncthreads();
    for (int ss = 128; ss; ss >>= 1) {
        if (tid < ss) red[tid] = fmaxf(red[tid], red[tid + ss]);
        __syncthreads();
    }
    m = red[0];
    __syncthreads();
    float p[8], sum = 0.f;
#pragma unroll
    for (int e = 0; e < 8; ++e) { p[e] = expf(s[e] - m); sum += p[e]; }
    red[tid] = sum;
    __syncthreads();
    for (int ss = 128; ss; ss >>= 1) {
        if (tid < ss) red[tid] += red[tid + ss];
        __syncthreads();
    }
    const float inv = 1.f / red[0];
    const int lim = ((i >> 7) + 1) << 7;
    if (k0 < lim) {
        short8 o;
#pragma unroll
        for (int e = 0; e < 8; ++e) o[e] = (short)f2b(p[e] * inv);
        *(short8*)(arow + k0) = o;
    }
}

// ---- pv: split-k partial O chunks (fp32 into sc area) ---------------------------
__global__ __launch_bounds__(256) void k_pv(const ushort_t* __restrict__ attn,
                                            const ushort_t* __restrict__ vcT,
                                            float* __restrict__ opbase, int g0) {
    const int byi = blockIdx.x, c = blockIdx.y, z = blockIdx.z;
    if (c * 4 > byi) return;
    const int hh = g0 + z;
    const int nt = min(4, byi + 1 - c * 4) * 4;
    const ushort_t* ap = attn + (size_t)z * NN + (size_t)(byi * 128) * 2048 + c * 512;
    const ushort_t* vp = vcT + (size_t)hh * 131072 + c * 512;
    float* op = opbase + (size_t)z * NN + (size_t)(c * 2048) * 64;
    __shared__ __align__(16) ushort_t lds[6144];
    const int l = threadIdx.x & 63, w = threadIdx.x >> 6, mb = w * 32;
    f32x4 acc[2][4] = {};
    for (int t = 0; t < nt; ++t) {
        const int k0 = t * 32;
        if (w < 2) stage_rows(ap + k0, 2048, lds, w * 4, w * 4 + 4);
        else if (w == 2) stage_rows(vp + k0, 2048, lds + 4096, 0, 4);
        __syncthreads();
        short8 fa[2], fb[4];
#pragma unroll
        for (int i = 0; i < 2; ++i) fa[i] = lfrag(lds, mb + i * 16, l);
#pragma unroll
        for (int j = 0; j < 4; ++j) fb[j] = lfrag(lds + 4096, j * 16, l);
#pragma unroll
        for (int i = 0; i < 2; ++i)
#pragma unroll
            for (int j = 0; j < 4; ++j) acc[i][j] = MFMA16(fa[i], fb[j], acc[i][j]);
        __syncthreads();
    }
#pragma unroll
    for (int i = 0; i < 2; ++i)
#pragma unroll
        for (int j = 0; j < 4; ++j)
#pragma unroll
            for (int r = 0; r < 4; ++r) {
                int gi = byi * 128 + mb + i * 16 + (l >> 4) * 4 + r;
                int d = j * 16 + (l & 15);
                op[(size_t)gi * 64 + d] = acc[i][j][r];
            }
}

// ---- pv combine: sum chunks -> bf16 attno ---------------------------------------
__global__ __launch_bounds__(256) void k_pvc(const float* __restrict__ opall,
                                             ushort_t* __restrict__ attno, int g0) {
    const int z = blockIdx.x >> 9, rem = blockIdx.x & 511;
    const int i = rem * 4 + (threadIdx.x >> 6), d = threadIdx.x & 63;
    const int hh = g0 + z, b = hh >> 3, h = hh & 7;
    const float* op = opall + (size_t)z * NN;
    const int nc = (i >> 9) + 1;
    float a = 0.f;
    for (int c = 0; c < nc; ++c) a += op[(size_t)(c * 2048 + i) * 64 + d];
    attno[(size_t)(b * 2048 + i) * 512 + h * 64 + d] = f2b(a);
}

// ---- final = attno @ Wout^T (single bf16) ---------------------------------------
__global__ __launch_bounds__(256) void k_outproj(const ushort_t* __restrict__ attno,
                                                 const ushort_t* __restrict__ woh,
                                                 float* __restrict__ out) {
    __shared__ __align__(16) ushort_t lds[8192];
    const int m0 = blockIdx.y * 128, n0 = blockIdx.x * 128;
    const int l = threadIdx.x & 63, w = threadIdx.x >> 6;
    const int mb = (w >> 1) * 64, nb = (w & 1) * 64;
    const ushort_t* pa = attno + (size_t)m0 * DI;
    const ushort_t* pb = woh + (size_t)n0 * DI;
    f32x4 acc[4][4] = {};
    for (int t = 0; t < 16; ++t) {
        const int k0 = t * 32;
        if (w < 2) stage_rows(pa + k0, DI, lds, w * 4, w * 4 + 4);
        else stage_rows(pb + k0, DI, lds + 4096, (w - 2) * 4, (w - 2) * 4 + 4);
        __syncthreads();
        short8 fa[4], fb[4];
#pragma unroll
        for (int i = 0; i < 4; ++i) fa[i] = lfrag(lds, mb + i * 16, l);
#pragma unroll
        for (int j = 0; j < 4; ++j) fb[j] = lfrag(lds + 4096, nb + j * 16, l);
#pragma unroll
        for (int i = 0; i < 4; ++i)
#pragma unroll
            for (int j = 0; j < 4; ++j) acc[i][j] = MFMA16(fa[i], fb[j], acc[i][j]);
        __syncthreads();
    }
#pragma unroll
    for (int i = 0; i < 4; ++i)
#pragma unroll
        for (int j = 0; j < 4; ++j)
#pragma unroll
            for (int r = 0; r < 4; ++r) {
                int m = m0 + mb + i * 16 + (l >> 4) * 4 + r;
                int n = n0 + nb + j * 16 + (l & 15);
                out[(size_t)m * DM + n] = acc[i][j][r];
            }
}

extern "C" void kernel_launch(void* const* d_in, const int* in_sizes, int n_in,
                              void* d_out, int out_size, void* d_ws, size_t ws_size,
                              hipStream_t stream) {
    const float* x = (const float*)d_in[0];
    const float* Wqkv = (const float*)d_in[1];
    const float* Wout = (const float*)d_in[2];
    float* out = (float*)d_out;

    const size_t fixedb = 58720256ull;   // qh + ql + vcT + attno
    const size_t perh = 50331648ull;     // t1 h/l + look h/l + sc(f32)
    int g = 0;
    for (int cand : {16, 8, 4, 2, 1})
        if (fixedb + perh * (size_t)cand <= ws_size) { g = cand; break; }
    if (!g) return;

    ushort_t* qh = (ushort_t*)d_ws;          // 12,582,912 el
    ushort_t* ql = qh + 12582912;            // 12,582,912 el
    ushort_t* vcT = ql + 12582912;           // 2,097,152 el
    ushort_t* attno = vcT + 2097152;         // 2,097,152 el
    ushort_t* pool = attno + 2097152;
    // cvt/proj phase aliases (dead after k_proj):
    ushort_t* xh = pool;
    ushort_t* xl = xh + 4194304;
    ushort_t* wh = xl + 4194304;
    ushort_t* wl = wh + 3145728;
    // group phase:
    ushort_t* t1h = pool;                                 // g*NN (also attn after softmax)
    ushort_t* t1l = t1h + (size_t)g * NN;
    ushort_t* lkh = t1l + (size_t)g * NN;
    ushort_t* lkl = lkh + (size_t)g * NN;
    float* scf = (float*)(lkl + (size_t)g * NN);          // g*NN f32 (also pv partials)
    // outproj phase:
    ushort_t* woh = pool;

    k_cvt<<<dim3(1024), 256, 0, stream>>>((const float4*)x, xh, xl, 1048576, 1);
    k_cvt<<<dim3(1024), 256, 0, stream>>>((const float4*)Wqkv, wh, wl, 786432, 1);
    k_proj<<<dim3(24, 32), 256, 0, stream>>>(xh, xl, wh, wl, qh, ql, vcT);

    for (int g0 = 0; g0 < 16; g0 += g) {
        k_tl<<<dim3(16, 16, 2 * g), 256, 0, stream>>>(qh, ql, t1h, t1l, lkh, lkl, g0);
        k_scores<<<dim3(16, 16, g), 256, 0, stream>>>(t1h, t1l, lkh, lkl, qh, ql, scf, g0);
        k_softmax<<<dim3(2048 * g), 256, 0, stream>>>(scf, t1h);
        k_pv<<<dim3(16, 4, g), 256, 0, stream>>>(t1h, vcT, scf, g0);
        k_pvc<<<dim3(512 * g), 256, 0, stream>>>(scf, attno, g0);
    }

    k_cvt<<<dim3(512), 256, 0, stream>>>((const float4*)Wout, woh, nullptr, 131072, 0);
    k_outproj<<<dim3(8, 32), 256, 0, stream>>>(attno, woh, out);
}

// Round 8
// 759.255 us; speedup vs baseline: 2.3125x; 1.3637x over previous
//
#include <hip/hip_runtime.h>
#include <cmath>

typedef unsigned short ushort_t;
typedef __attribute__((ext_vector_type(8))) short short8;
typedef __attribute__((ext_vector_type(4))) float f32x4;
typedef __attribute__((ext_vector_type(4))) short short4v;

static constexpr int NSEQ = 2048, DM = 1024, DI = 512;
static constexpr size_t NN = (size_t)NSEQ * NSEQ;

__device__ __forceinline__ ushort_t f2b(float v) {
    unsigned u = __float_as_uint(v);
    return (ushort_t)((u + 0x7fffu + ((u >> 16) & 1u)) >> 16);  // RTNE
}
__device__ __forceinline__ float b2f(ushort_t b) { return __uint_as_float(((unsigned)b) << 16); }
__device__ __forceinline__ float sigm(float x) { return 1.f / (1.f + expf(-x)); }
__device__ __forceinline__ float silu(float x) { return x / (1.f + expf(-x)); }

#define MFMA16(a, b, c) __builtin_amdgcn_mfma_f32_16x16x32_bf16(a, b, c, 0, 0, 0)

// ---- async global->LDS staging, source pre-swizzled (rule #21) ------------------
// LDS tile is [rows][32] linear; 16B chunk at phys (row, l&3) holds logical chunk
// (l&3)^((row>>1)&3). Reads use the same XOR -> conflict-free (r5-measured 0).
__device__ __forceinline__ void gll16(const ushort_t* g, ushort_t* l) {
    __builtin_amdgcn_global_load_lds((const __attribute__((address_space(1))) void*)g,
                                     (__attribute__((address_space(3))) void*)l, 16, 0, 0);
}
__device__ __forceinline__ void stage16(const ushort_t* g, int ldg, ushort_t* lds, int q) {
    const int l = threadIdx.x & 63;
    const int row = l >> 2;
    const int ch = (l & 3) ^ ((l >> 3) & 3);     // logical chunk for this lane's slot
    gll16(g + (size_t)(q * 16 + row) * ldg + ch * 8, lds + q * 512);
}
__device__ __forceinline__ short8 lfrag(const ushort_t* t, int row0, int lane) {
    const int row = row0 + (lane & 15);
    const int ch = (lane >> 4) ^ ((row >> 1) & 3);
    return *(const short8*)(t + row * 32 + (ch << 3));
}
// hi/lo 4x4 tile step: buffer = [Ah|Al|Bh|Bl] at 4096-elem strides
__device__ __forceinline__ void mm48(const ushort_t* buf, int mb, int nb, int lane,
                                     f32x4 (&acc)[4][4]) {
    short8 fah[4], fal[4], fbh[4], fbl[4];
#pragma unroll
    for (int i = 0; i < 4; ++i) {
        fah[i] = lfrag(buf, mb + i * 16, lane);
        fal[i] = lfrag(buf + 4096, mb + i * 16, lane);
    }
#pragma unroll
    for (int j = 0; j < 4; ++j) {
        fbh[j] = lfrag(buf + 8192, nb + j * 16, lane);
        fbl[j] = lfrag(buf + 12288, nb + j * 16, lane);
    }
#pragma unroll
    for (int i = 0; i < 4; ++i)
#pragma unroll
        for (int j = 0; j < 4; ++j) {
            acc[i][j] = MFMA16(fah[i], fbh[j], acc[i][j]);
            acc[i][j] = MFMA16(fah[i], fbl[j], acc[i][j]);
            acc[i][j] = MFMA16(fal[i], fbh[j], acc[i][j]);
        }
}
// descending-length triangular pair decode: p in [0,136) -> (lo, lo+d), d=15..0
__device__ __forceinline__ void pair_decode(int p, int& lo, int& d) {
    d = 15;
    int cnt = 1;
    while (p >= cnt) { p -= cnt; --d; cnt = 16 - d; }
    lo = p;
}

// ---- one-shot f32 -> bf16 hi(/lo) -----------------------------------------------
__global__ __launch_bounds__(256) void k_cvt(const float4* __restrict__ src,
                                             ushort_t* __restrict__ hi,
                                             ushort_t* __restrict__ lo, int n4, int has_lo) {
    for (int i = blockIdx.x * 256 + threadIdx.x; i < n4; i += gridDim.x * 256) {
        float4 f = src[i];
        float a[4] = {f.x, f.y, f.z, f.w};
        short4v hv, lv;
#pragma unroll
        for (int j = 0; j < 4; ++j) {
            ushort_t h = f2b(a[j]);
            hv[j] = (short)h;
            lv[j] = (short)f2b(a[j] - b2f(h));
        }
        *(short4v*)(hi + (size_t)i * 4) = hv;
        if (has_lo) *(short4v*)(lo + (size_t)i * 4) = lv;
    }
}

// ---- proj: qkv = x @ Wqkv^T (hi/lo), dbuf pipelined, scatter + vcT --------------
__global__ __launch_bounds__(256) void k_proj(const ushort_t* __restrict__ xh,
                                              const ushort_t* __restrict__ xl,
                                              const ushort_t* __restrict__ wh,
                                              const ushort_t* __restrict__ wl,
                                              ushort_t* __restrict__ qh, ushort_t* __restrict__ ql,
                                              ushort_t* __restrict__ vcT) {
    __shared__ __align__(16) ushort_t lds[2][16384];
    const int m0 = blockIdx.y * 128, n0 = blockIdx.x * 128;
    const int l = threadIdx.x & 63, w = threadIdx.x >> 6;
    const int mb = (w >> 1) * 64, nb = (w & 1) * 64;
    const ushort_t* mats[4] = {xh + (size_t)m0 * DM, xl + (size_t)m0 * DM,
                               wh + (size_t)n0 * DM, wl + (size_t)n0 * DM};
    auto STAGE = [&](int t, ushort_t* buf) {
        const ushort_t* src = mats[w] + t * 32;
        for (int q = 0; q < 8; ++q) stage16(src, DM, buf + w * 4096, q);
    };
    STAGE(0, lds[0]);
    __syncthreads();
    f32x4 acc[4][4] = {};
    for (int t = 0; t < 32; ++t) {
        if (t + 1 < 32) STAGE(t + 1, lds[(t + 1) & 1]);
        mm48(lds[t & 1], mb, nb, l, acc);
        __syncthreads();
    }
#pragma unroll
    for (int i = 0; i < 4; ++i)
#pragma unroll
        for (int j = 0; j < 4; ++j)
#pragma unroll
            for (int r = 0; r < 4; ++r) {
                int m = m0 + mb + i * 16 + (l >> 4) * 4 + r;
                int n = n0 + nb + j * 16 + (l & 15);
                float v = acc[i][j][r];
                int tt = n >> 9, head = (n >> 6) & 7, dd = n & 63;
                int b = m >> 11, np = m & 2047;
                if (tt == 0 || tt == 3) v *= 0.125f;
                ushort_t h = f2b(v), lo = f2b(v - b2f(h));
                size_t off = (size_t)(tt * 16 + b * 8 + head) * 131072 + (size_t)np * 64 + dd;
                qh[off] = h;
                ql[off] = lo;
                if (tt == 5) vcT[(size_t)(b * 8 + head) * 131072 + (size_t)dd * 2048 + np] = h;
            }
}

// ---- tl: mode0 t1 = mask_lower(qc@vu^T), mode1 look = mask_up(sigm(qu@ku^T)) ----
__global__ __launch_bounds__(256) void k_tl(const ushort_t* __restrict__ qkvh,
                                            const ushort_t* __restrict__ qkvl,
                                            ushort_t* __restrict__ t1h, ushort_t* __restrict__ t1l,
                                            ushort_t* __restrict__ lkh, ushort_t* __restrict__ lkl,
                                            int g0) {
    const int mode = blockIdx.x & 1, z = blockIdx.x >> 1, hh = g0 + z;
    int lo_t, d;
    pair_decode(blockIdx.y, lo_t, d);
    const int by = mode ? lo_t : lo_t + d;      // mode0: by=i tile (>=bx); mode1: by=k (<=bx)
    const int bx = mode ? lo_t + d : lo_t;
    const int ta = mode ? 0 : 3, tb = mode ? 1 : 2;
    __shared__ __align__(16) ushort_t lds[2][16384];
    const int l = threadIdx.x & 63, w = threadIdx.x >> 6;
    const int mb = (w >> 1) * 64, nb = (w & 1) * 64;
    const ushort_t* mats[4] = {
        qkvh + (size_t)(ta * 16 + hh) * 131072 + (size_t)(by * 128) * 64,
        qkvl + (size_t)(ta * 16 + hh) * 131072 + (size_t)(by * 128) * 64,
        qkvh + (size_t)(tb * 16 + hh) * 131072 + (size_t)(bx * 128) * 64,
        qkvl + (size_t)(tb * 16 + hh) * 131072 + (size_t)(bx * 128) * 64};
    auto STAGE = [&](int t, ushort_t* buf) {
        const ushort_t* src = mats[w] + t * 32;
        for (int q = 0; q < 8; ++q) stage16(src, 64, buf + w * 4096, q);
    };
    STAGE(0, lds[0]);
    __syncthreads();
    f32x4 acc[4][4] = {};
    for (int t = 0; t < 2; ++t) {
        if (t == 0) STAGE(1, lds[1]);
        mm48(lds[t & 1], mb, nb, l, acc);
        __syncthreads();
    }
    if (mode == 0) {
        ushort_t* th = t1h + (size_t)z * NN;
        ushort_t* tl = t1l + (size_t)z * NN;
#pragma unroll
        for (int i = 0; i < 4; ++i)
#pragma unroll
            for (int j = 0; j < 4; ++j)
#pragma unroll
                for (int r = 0; r < 4; ++r) {
                    int gi = by * 128 + mb + i * 16 + (l >> 4) * 4 + r;
                    int gj = bx * 128 + nb + j * 16 + (l & 15);
                    float v = (gj <= gi) ? acc[i][j][r] : 0.f;
                    ushort_t h = f2b(v);
                    th[(size_t)gi * 2048 + gj] = h;
                    tl[(size_t)gi * 2048 + gj] = f2b(v - b2f(h));
                }
    } else {
        ushort_t* lh = lkh + (size_t)z * NN;
        ushort_t* ll = lkl + (size_t)z * NN;
#pragma unroll
        for (int i = 0; i < 4; ++i)
#pragma unroll
            for (int j = 0; j < 4; ++j)
#pragma unroll
                for (int r = 0; r < 4; ++r) {
                    int gk = by * 128 + mb + i * 16 + (l >> 4) * 4 + r;
                    int gj = bx * 128 + nb + j * 16 + (l & 15);
                    float v = (gj > gk) ? sigm(acc[i][j][r]) : 0.f;
                    ushort_t h = f2b(v);
                    lh[(size_t)gk * 2048 + gj] = h;
                    ll[(size_t)gk * 2048 + gj] = f2b(v - b2f(h));
                }
    }
}

// ---- scores = qc_s@kc^T - silu(t1 @ look^T), dbuf, balanced ---------------------
__global__ __launch_bounds__(256) void k_scores(const ushort_t* __restrict__ t1h,
                                                const ushort_t* __restrict__ t1l,
                                                const ushort_t* __restrict__ lkh,
                                                const ushort_t* __restrict__ lkl,
                                                const ushort_t* __restrict__ qkvh,
                                                const ushort_t* __restrict__ qkvl,
                                                float* __restrict__ sc, int g0) {
    const int z = blockIdx.x, hh = g0 + z;
    int bxk, d;
    pair_decode(blockIdx.y, bxk, d);
    const int byi = bxk + d;
    __shared__ __align__(16) ushort_t lds[2][16384];
    const int l = threadIdx.x & 63, w = threadIdx.x >> 6;
    const int mb = (w >> 1) * 64, nb = (w & 1) * 64;
    const int nsu = (d + 1) * 4, nt = nsu + 2;
    const ushort_t* jmats[4] = {
        t1h + (size_t)z * NN + (size_t)(byi * 128) * 2048 + bxk * 128,
        t1l + (size_t)z * NN + (size_t)(byi * 128) * 2048 + bxk * 128,
        lkh + (size_t)z * NN + (size_t)(bxk * 128) * 2048 + bxk * 128,
        lkl + (size_t)z * NN + (size_t)(bxk * 128) * 2048 + bxk * 128};
    const ushort_t* smats[4] = {
        qkvh + (size_t)(3 * 16 + hh) * 131072 + (size_t)(byi * 128) * 64,
        qkvl + (size_t)(3 * 16 + hh) * 131072 + (size_t)(byi * 128) * 64,
        qkvh + (size_t)(4 * 16 + hh) * 131072 + (size_t)(bxk * 128) * 64,
        qkvl + (size_t)(4 * 16 + hh) * 131072 + (size_t)(bxk * 128) * 64};
    auto STAGE = [&](int t, ushort_t* buf) {
        const ushort_t* src;
        int ldg;
        if (t < nsu) { src = jmats[w] + t * 32; ldg = 2048; }
        else { src = smats[w] + (t - nsu) * 32; ldg = 64; }
        for (int q = 0; q < 8; ++q) stage16(src, ldg, buf + w * 4096, q);
    };
    STAGE(0, lds[0]);
    __syncthreads();
    f32x4 acc[4][4] = {};
    for (int t = 0; t < nt; ++t) {
        if (t + 1 < nt) STAGE(t + 1, lds[(t + 1) & 1]);
        if (t == nsu) {
#pragma unroll
            for (int i = 0; i < 4; ++i)
#pragma unroll
                for (int j = 0; j < 4; ++j)
#pragma unroll
                    for (int r = 0; r < 4; ++r) acc[i][j][r] = -silu(acc[i][j][r]);
        }
        mm48(lds[t & 1], mb, nb, l, acc);
        __syncthreads();
    }
    float* so = sc + (size_t)z * NN;
#pragma unroll
    for (int i = 0; i < 4; ++i)
#pragma unroll
        for (int j = 0; j < 4; ++j)
#pragma unroll
            for (int r = 0; r < 4; ++r) {
                int gi = byi * 128 + mb + i * 16 + (l >> 4) * 4 + r;
                int gk = bxk * 128 + nb + j * 16 + (l & 15);
                if (gk <= gi) so[(size_t)gi * 2048 + gk] = acc[i][j][r];
            }
}

// ---- row softmax (k<=i) -> bf16 attn (into t1h), zero-pad to 128-boundary -------
__global__ __launch_bounds__(256) void k_softmax(const float* __restrict__ scb,
                                                 ushort_t* __restrict__ attn) {
    const int z = blockIdx.x >> 11, i = blockIdx.x & 2047;
    const float* scr = scb + (size_t)z * NN + (size_t)i * 2048;
    ushort_t* arow = attn + (size_t)z * NN + (size_t)i * 2048;
    const int tid = threadIdx.x, k0 = tid * 8;
    float4 a0 = *(const float4*)(scr + k0), a1 = *(const float4*)(scr + k0 + 4);
    float sv[8] = {a0.x, a0.y, a0.z, a0.w, a1.x, a1.y, a1.z, a1.w};
    float s[8];
    float m = -3e38f;
#pragma unroll
    for (int e = 0; e < 8; ++e) {
        s[e] = (k0 + e <= i) ? sv[e] : -3e38f;
        m = fmaxf(m, s[e]);
    }
    __shared__ float red[256];
    red[tid] = m;
    __syncthreads();
    for (int ss = 128; ss; ss >>= 1) {
        if (tid < ss) red[tid] = fmaxf(red[tid], red[tid + ss]);
        __syncthreads();
    }
    m = red[0];
    __syncthreads();
    float p[8], sum = 0.f;
#pragma unroll
    for (int e = 0; e < 8; ++e) { p[e] = expf(s[e] - m); sum += p[e]; }
    red[tid] = sum;
    __syncthreads();
    for (int ss = 128; ss; ss >>= 1) {
        if (tid < ss) red[tid] += red[tid + ss];
        __syncthreads();
    }
    const float inv = 1.f / red[0];
    const int lim = ((i >> 7) + 1) << 7;
    if (k0 < lim) {
        short8 o;
#pragma unroll
        for (int e = 0; e < 8; ++e) o[e] = (short)f2b(p[e] * inv);
        *(short8*)(arow + k0) = o;
    }
}

// ---- pv: split-k partial O chunks (fp32 into sc area), dbuf, balanced -----------
__global__ __launch_bounds__(256) void k_pv(const ushort_t* __restrict__ attn,
                                            const ushort_t* __restrict__ vcT,
                                            float* __restrict__ opbase, int g0) {
    const int z = blockIdx.x, hh = g0 + z;
    int pp = blockIdx.y, byi = 15, c;
    for (;;) {
        int cb = (byi >> 2) + 1;
        if (pp < cb) { c = pp; break; }
        pp -= cb;
        --byi;
    }
    const int nt = min(4, byi + 1 - c * 4) * 4;
    const ushort_t* ap = attn + (size_t)z * NN + (size_t)(byi * 128) * 2048 + c * 512;
    const ushort_t* vp = vcT + (size_t)hh * 131072 + c * 512;
    float* op = opbase + (size_t)z * NN + (size_t)(c * 2048) * 64;
    __shared__ __align__(16) ushort_t lds[2][6144];
    const int l = threadIdx.x & 63, w = threadIdx.x >> 6, mb = w * 32;
    auto STAGE = [&](int t, ushort_t* buf) {
        const int k0 = t * 32;
        for (int u = w * 3; u < w * 3 + 3; ++u) {
            if (u < 8) stage16(ap + k0, 2048, buf, u);
            else stage16(vp + k0, 2048, buf + 4096, u - 8);
        }
    };
    STAGE(0, lds[0]);
    __syncthreads();
    f32x4 acc[2][4] = {};
    for (int t = 0; t < nt; ++t) {
        if (t + 1 < nt) STAGE(t + 1, lds[(t + 1) & 1]);
        const ushort_t* buf = lds[t & 1];
        short8 fa[2], fb[4];
#pragma unroll
        for (int i = 0; i < 2; ++i) fa[i] = lfrag(buf, mb + i * 16, l);
#pragma unroll
        for (int j = 0; j < 4; ++j) fb[j] = lfrag(buf + 4096, j * 16, l);
#pragma unroll
        for (int i = 0; i < 2; ++i)
#pragma unroll
            for (int j = 0; j < 4; ++j) acc[i][j] = MFMA16(fa[i], fb[j], acc[i][j]);
        __syncthreads();
    }
#pragma unroll
    for (int i = 0; i < 2; ++i)
#pragma unroll
        for (int j = 0; j < 4; ++j)
#pragma unroll
            for (int r = 0; r < 4; ++r) {
                int gi = byi * 128 + mb + i * 16 + (l >> 4) * 4 + r;
                int dd = j * 16 + (l & 15);
                op[(size_t)gi * 64 + dd] = acc[i][j][r];
            }
}

// ---- pv combine: sum chunks -> bf16 attno ---------------------------------------
__global__ __launch_bounds__(256) void k_pvc(const float* __restrict__ opall,
                                             ushort_t* __restrict__ attno, int g0) {
    const int z = blockIdx.x >> 9, rem = blockIdx.x & 511;
    const int i = rem * 4 + (threadIdx.x >> 6), d = threadIdx.x & 63;
    const int hh = g0 + z, b = hh >> 3, h = hh & 7;
    const float* op = opall + (size_t)z * NN;
    const int nc = (i >> 9) + 1;
    float a = 0.f;
    for (int c = 0; c < nc; ++c) a += op[(size_t)(c * 2048 + i) * 64 + d];
    attno[(size_t)(b * 2048 + i) * 512 + h * 64 + d] = f2b(a);
}

// ---- final = attno @ Wout^T (single bf16), dbuf ---------------------------------
__global__ __launch_bounds__(256) void k_outproj(const ushort_t* __restrict__ attno,
                                                 const ushort_t* __restrict__ woh,
                                                 float* __restrict__ out) {
    __shared__ __align__(16) ushort_t lds[2][8192];
    const int m0 = blockIdx.y * 128, n0 = blockIdx.x * 128;
    const int l = threadIdx.x & 63, w = threadIdx.x >> 6;
    const int mb = (w >> 1) * 64, nb = (w & 1) * 64;
    const ushort_t* pa = attno + (size_t)m0 * DI;
    const ushort_t* pb = woh + (size_t)n0 * DI;
    auto STAGE = [&](int t, ushort_t* buf) {
        const int k0 = t * 32;
        for (int u = w * 4; u < w * 4 + 4; ++u) {
            if (u < 8) stage16(pa + k0, DI, buf, u);
            else stage16(pb + k0, DI, buf + 4096, u - 8);
        }
    };
    STAGE(0, lds[0]);
    __syncthreads();
    f32x4 acc[4][4] = {};
    for (int t = 0; t < 16; ++t) {
        if (t + 1 < 16) STAGE(t + 1, lds[(t + 1) & 1]);
        const ushort_t* buf = lds[t & 1];
        short8 fa[4], fb[4];
#pragma unroll
        for (int i = 0; i < 4; ++i) fa[i] = lfrag(buf, mb + i * 16, l);
#pragma unroll
        for (int j = 0; j < 4; ++j) fb[j] = lfrag(buf + 4096, nb + j * 16, l);
#pragma unroll
        for (int i = 0; i < 4; ++i)
#pragma unroll
            for (int j = 0; j < 4; ++j) acc[i][j] = MFMA16(fa[i], fb[j], acc[i][j]);
        __syncthreads();
    }
#pragma unroll
    for (int i = 0; i < 4; ++i)
#pragma unroll
        for (int j = 0; j < 4; ++j)
#pragma unroll
            for (int r = 0; r < 4; ++r) {
                int m = m0 + mb + i * 16 + (l >> 4) * 4 + r;
                int n = n0 + nb + j * 16 + (l & 15);
                out[(size_t)m * DM + n] = acc[i][j][r];
            }
}

extern "C" void kernel_launch(void* const* d_in, const int* in_sizes, int n_in,
                              void* d_out, int out_size, void* d_ws, size_t ws_size,
                              hipStream_t stream) {
    const float* x = (const float*)d_in[0];
    const float* Wqkv = (const float*)d_in[1];
    const float* Wout = (const float*)d_in[2];
    float* out = (float*)d_out;

    const size_t fixedb = 58720256ull;   // qh + ql + vcT + attno
    const size_t perh = 50331648ull;     // t1 h/l + look h/l + sc(f32)
    int g = 0;
    for (int cand : {16, 8, 4, 2, 1})
        if (fixedb + perh * (size_t)cand <= ws_size) { g = cand; break; }
    if (!g) return;

    ushort_t* qh = (ushort_t*)d_ws;          // 12,582,912 el
    ushort_t* ql = qh + 12582912;            // 12,582,912 el
    ushort_t* vcT = ql + 12582912;           // 2,097,152 el
    ushort_t* attno = vcT + 2097152;         // 2,097,152 el
    ushort_t* pool = attno + 2097152;
    // cvt/proj phase aliases (dead after k_proj):
    ushort_t* xh = pool;
    ushort_t* xl = xh + 4194304;
    ushort_t* wh = xl + 4194304;
    ushort_t* wl = wh + 3145728;
    // group phase:
    ushort_t* t1h = pool;                                 // g*NN (attn after softmax)
    ushort_t* t1l = t1h + (size_t)g * NN;
    ushort_t* lkh = t1l + (size_t)g * NN;
    ushort_t* lkl = lkh + (size_t)g * NN;
    float* scf = (float*)(lkl + (size_t)g * NN);          // g*NN f32 (pv partials too)
    // outproj phase:
    ushort_t* woh = pool;

    k_cvt<<<dim3(1024), 256, 0, stream>>>((const float4*)x, xh, xl, 1048576, 1);
    k_cvt<<<dim3(1024), 256, 0, stream>>>((const float4*)Wqkv, wh, wl, 786432, 1);
    k_proj<<<dim3(24, 32), 256, 0, stream>>>(xh, xl, wh, wl, qh, ql, vcT);

    for (int g0 = 0; g0 < 16; g0 += g) {
        k_tl<<<dim3(2 * g, 136), 256, 0, stream>>>(qh, ql, t1h, t1l, lkh, lkl, g0);
        k_scores<<<dim3(g, 136), 256, 0, stream>>>(t1h, t1l, lkh, lkl, qh, ql, scf, g0);
        k_softmax<<<dim3(2048 * g), 256, 0, stream>>>(scf, t1h);
        k_pv<<<dim3(g, 40), 256, 0, stream>>>(t1h, vcT, scf, g0);
        k_pvc<<<dim3(512 * g), 256, 0, stream>>>(scf, attno, g0);
    }

    k_cvt<<<dim3(512), 256, 0, stream>>>((const float4*)Wout, woh, nullptr, 131072, 0);
    k_outproj<<<dim3(8, 32), 256, 0, stream>>>(attno, woh, out);
}